// Round 20
// baseline (318.288 us; speedup 1.0000x reference)
//
#include <hip/hip_runtime.h>

#define INV_SQRT2 0.70710678118654752440f
#define KH 0.35355339059327376220f   // INV_SQRT2 * 0.5 (output scale folded in)

// Stage-2 filter table as constexpr: compile-time indices after unroll ->
// coefficients fold to immediates; structural zeros kill 20% of FMAs.
constexpr float c_first[2][10][2] = {
  { { 0.00000000000000f,  0.00000000000000f},
    {-0.08838834764832f, -0.01122679215254f},
    { 0.08838834764832f,  0.01122679215254f},
    { 0.69587998903400f,  0.08838834764832f},
    { 0.69587998903400f,  0.08838834764832f},
    { 0.08838834764832f, -0.69587998903400f},
    {-0.08838834764832f,  0.69587998903400f},
    { 0.01122679215254f, -0.08838834764832f},
    { 0.01122679215254f, -0.08838834764832f},
    { 0.00000000000000f,  0.00000000000000f} },
  { { 0.01122679215254f,  0.00000000000000f},
    { 0.01122679215254f,  0.00000000000000f},
    {-0.08838834764832f, -0.08838834764832f},
    { 0.08838834764832f, -0.08838834764832f},
    { 0.69587998903400f,  0.69587998903400f},
    { 0.69587998903400f, -0.69587998903400f},
    { 0.08838834764832f,  0.08838834764832f},
    {-0.08838834764832f,  0.08838834764832f},
    { 0.00000000000000f,  0.01122679215254f},
    { 0.00000000000000f, -0.01122679215254f} }
};

// Q-shift table, constexpr: stage1 dispatches a templated body per (M,N)
// combo, so all indices are compile-time -> immediates + zero folding.
constexpr float cq[2][10][2] = {
  { { 0.03516384f,  0.00000000f},
    { 0.00000000f,  0.00000000f},
    {-0.08832942f, -0.11430184f},
    { 0.23389032f,  0.00000000f},
    { 0.76027237f,  0.58751830f},
    { 0.58751830f, -0.76027237f},
    { 0.00000000f,  0.23389032f},
    {-0.11430184f,  0.08832942f},
    { 0.00000000f,  0.00000000f},
    { 0.00000000f, -0.03516384f} },
  { { 0.00000000f, -0.03516384f},
    { 0.00000000f,  0.00000000f},
    {-0.11430184f,  0.08832942f},
    { 0.00000000f,  0.23389032f},
    { 0.58751830f, -0.76027237f},
    { 0.76027237f,  0.58751830f},
    { 0.23389032f,  0.00000000f},
    {-0.08832942f, -0.11430184f},
    { 0.00000000f,  0.00000000f},
    { 0.03516384f,  0.00000000f} }
};

// ---------------------------------------------------------------------------
// Stage 1: LDS-row-staged (R19 proven form, ~20.5us). Reg-staged loads ->
// pre-butterfly -> ds_write; single buffer + split barriers; planar
// [array][slot] pitch 144. Butterfly sign compile-time; K folds into
// coefficient immediates. LDS padded to 27,200 B -> 6 blocks/CU.
// ---------------------------------------------------------------------------
template<int M, int N>
__device__ __forceinline__ void s1_body(
    const float* __restrict__ lows, const float* __restrict__ highs1,
    float* __restrict__ lo2, float* __restrict__ lds)
{
  constexpr int HIN = 128, WIN = 128, C = 3, B = 16;
  constexpr int ROWF  = WIN * C;        // 384
  constexpr int ROWO  = 2 * WIN * C;    // 768
  constexpr int PLANE = HIN * WIN * C;  // 49152
  constexpr int SEG   = 16;
  constexpr int NI    = SEG + 4;        // 20 row phases
  constexpr int PITCH = 144;            // dwords per array slice (140 used)
  constexpr int combo = M * 2 + N;
  constexpr int pa = (M == N) ? 0 : 1;
  constexpr int pb = (M == N) ? 3 : 2;
  constexpr float K = INV_SQRT2;

  const int tid = threadIdx.x;          // 0..127
  const int jj  = blockIdx.x * 128 + tid;  // 0..383 = (t,c)
  const int c   = jj % 3;
  const int t   = jj / 3;
  const int b   = blockIdx.z & 15;

  const float* lo = lows + (combo * B + b) * PLANE;
  const int bandStride = B * PLANE;
  const float* hA = highs1 + (pa * 3 * B + b) * PLANE;
  const float* hB = highs1 + (pb * 3 * B + b) * PLANE;

  int j1 = jj - 6;   if (j1 < 0)     j1 += ROWF;   // slot tid (full wave)
  int j2 = jj + 122; if (j2 >= ROWF) j2 -= ROWF;   // slot 128+tid (tid<12)
  const bool halo = (tid < 12);

  float lae[5], lao[5], hae[5], hao[5];
#pragma unroll
  for (int k = 0; k < 5; ++k) { lae[k]=0.f; lao[k]=0.f; hae[k]=0.f; hao[k]=0.f; }

  const int s0 = blockIdx.y * SEG;
  float* outp = lo2 + (combo * B + b) * (4 * PLANE);

  float rl, rA0, rB0, rA1, rB1, rA2, rB2;
  float hl = 0.f, hA0v = 0.f, hB0v = 0.f, hA1v = 0.f,
        hB1v = 0.f, hA2v = 0.f, hB2v = 0.f;

#define BFY(a_, b_) ((M == 0) ? ((a_) + (b_)) : ((a_) - (b_)))

#define S1_LOAD(I)                                                           \
  {                                                                          \
    const int rb_ = ((s0 - 2 + (I)) & (HIN - 1)) * ROWF;                     \
    rl  = lo[rb_ + j1];                                                      \
    rA0 = hA[rb_ + j1];                rB0 = hB[rb_ + j1];                   \
    rA1 = hA[rb_ + j1 + bandStride];   rB1 = hB[rb_ + j1 + bandStride];      \
    rA2 = hA[rb_ + j1 + 2*bandStride]; rB2 = hB[rb_ + j1 + 2*bandStride];    \
    if (halo) {                                                              \
      hl   = lo[rb_ + j2];                                                   \
      hA0v = hA[rb_ + j2];                hB0v = hB[rb_ + j2];               \
      hA1v = hA[rb_ + j2 + bandStride];   hB1v = hB[rb_ + j2 + bandStride];  \
      hA2v = hA[rb_ + j2 + 2*bandStride]; hB2v = hB[rb_ + j2 + 2*bandStride];\
    }                                                                        \
  }

#define S1_WRITE()                                                           \
  {                                                                          \
    lds[0*PITCH + tid] = rl;                                                 \
    lds[1*PITCH + tid] = BFY(rA0, rB0);                                      \
    lds[2*PITCH + tid] = BFY(rA1, rB1);                                      \
    lds[3*PITCH + tid] = BFY(rA2, rB2);                                      \
    if (halo) {                                                              \
      lds[0*PITCH + 128 + tid] = hl;                                         \
      lds[1*PITCH + 128 + tid] = BFY(hA0v, hB0v);                            \
      lds[2*PITCH + 128 + tid] = BFY(hA1v, hB1v);                            \
      lds[3*PITCH + 128 + tid] = BFY(hA2v, hB2v);                            \
    }                                                                        \
  }

  S1_LOAD(0);
  S1_WRITE();
  __syncthreads();

#pragma unroll 1
  for (int uo = 0; uo < 4; ++uo) {
#pragma unroll
    for (int k = 0; k < 5; ++k) {
      const int i = uo * 5 + k;           // window slot = k (static; i%5==k)

      if (i < NI - 1) {
        S1_LOAD(i + 1);
        __builtin_amdgcn_sched_barrier(0);
      }

      float aLe=0.f, aLo=0.f, aHe=0.f, aHo=0.f;
#pragma unroll
      for (int p = 0; p < 5; ++p) {
        const int sl = tid + (12 - 3*p);
        const float lv  = lds[0*PITCH + sl];
        const float lhv = lds[1*PITCH + sl];
        const float hlv = lds[2*PITCH + sl];
        const float hhv = lds[3*PITCH + sl];
        const float ce0  = cq[N][9-2*p][0];
        const float co0  = cq[N][8-2*p][0];
        const float ce1K = cq[N][9-2*p][1] * K;
        const float co1K = cq[N][8-2*p][1] * K;
        const float ce0K = ce0 * K;
        const float co0K = co0 * K;
        aLe += ce0  * lv  + ce1K * lhv;
        aLo += co0  * lv  + co1K * lhv;
        aHe += ce0K * hlv + ce1K * hhv;
        aHo += co0K * hlv + co1K * hhv;
      }
      lae[k]=aLe; lao[k]=aLo; hae[k]=aHe; hao[k]=aHo;

      if (i >= 4) {
        const int s = s0 + i - 4;
        float o00=0.f, o01=0.f, o10=0.f, o11=0.f;
#pragma unroll
        for (int p = 0; p < 5; ++p) {
          const int kk = (k - p + 5) % 5;
          const float f0l = cq[M][9-2*p][0], f0h = cq[M][9-2*p][1];
          const float f1l = cq[M][8-2*p][0], f1h = cq[M][8-2*p][1];
          o00 += f0l*lae[kk] + f0h*hae[kk];
          o01 += f0l*lao[kk] + f0h*hao[kk];
          o10 += f1l*lae[kk] + f1h*hae[kk];
          o11 += f1l*lao[kk] + f1h*hao[kk];
        }
        float* q = outp + (2*s) * ROWO + (2*t) * C + c;
        q[0]        = o00;
        q[C]        = o01;
        q[ROWO]     = o10;
        q[ROWO + C] = o11;
      }

      __syncthreads();
      if (i < NI - 1) {
        S1_WRITE();
      }
      __syncthreads();
    }
  }
#undef S1_LOAD
#undef S1_WRITE
#undef BFY
}

__global__ __launch_bounds__(128, 3) void idtcwt_stage1(
    const float* __restrict__ lows, const float* __restrict__ highs1,
    float* __restrict__ lo2)
{
  __shared__ float s1lds[6800];         // 27,200 B -> 6 blocks/CU
  const int combo = blockIdx.z >> 4;
  if      (combo == 0) s1_body<0,0>(lows, highs1, lo2, s1lds);
  else if (combo == 1) s1_body<0,1>(lows, highs1, lo2, s1lds);
  else if (combo == 2) s1_body<1,0>(lows, highs1, lo2, s1lds);
  else                 s1_body<1,1>(lows, highs1, lo2, s1lds);
}

// ---------------------------------------------------------------------------
// Stage 2: R15 structure at DOUBLED OCCUPANCY. The lean form measures 68
// VGPRs (stable across R15/R18/R19) — it now fits a 6-blocks/CU budget
// (512/6 = 85), which R10/R11's ~100-reg versions could not. SEG=8: grid
// 1536 = 6 blocks/CU supplied = 24 waves/CU (2x R19). LDS padded to
// 26,624 B (exactly 6-block LDS cap -> allocator budget 85 >= ~72 need).
// Window stays period 5 (slot=i%5 valid for any NI; avoids R10's +8 regs).
// Accepted cost: 12 iters/8 rows (+20% work, FETCH ~184MB, HBM has room).
// ---------------------------------------------------------------------------
__global__ __launch_bounds__(256, 6) void idtcwt_stage2(
    const float* __restrict__ lo2, const float* __restrict__ highs0,
    float* __restrict__ out)
{
  constexpr int HIN = 256, WIN = 256, C = 3, B = 16;
  constexpr int ROWF  = WIN * C;        // 768 floats per input row
  constexpr int ROWO  = 2 * WIN * C;    // 1536
  constexpr int PLANE = HIN * WIN * C;  // 196608
  constexpr int OPLANE = 512 * 512 * C; // 786432
  constexpr int SEG   = 8;
  constexpr int NI    = SEG + 4;        // 12 row phases
  constexpr int PITCH = 5;              // float4s per slot (16 arrays + pad)
  constexpr int LDSV4 = 1664;           // 26,624 B -> 6 blk/CU, budget 85

  __shared__ float4 lds4[LDSV4];        // 21,760 B used; padded for budget

  const int tid = threadIdx.x;
  const int jj  = blockIdx.x * 256 + tid;  // 0..767 = (t,c)
  const int c   = jj % 3;
  const int t   = jj / 3;
  const int b   = blockIdx.z;

  const int bandStride = B * PLANE;
  const float* a0  = lo2 + (0 * B + b) * PLANE;           // l00
  const float* a1  = lo2 + (1 * B + b) * PLANE;           // l01
  const float* a2  = lo2 + (2 * B + b) * PLANE;           // l10
  const float* a3  = lo2 + (3 * B + b) * PLANE;           // l11
  const float* h00b0 = highs0 + (0 * 3 * B + b) * PLANE;
  const float* h01b0 = highs0 + (1 * 3 * B + b) * PLANE;
  const float* h10b0 = highs0 + (2 * 3 * B + b) * PLANE;
  const float* h11b0 = highs0 + (3 * 3 * B + b) * PLANE;
  const float* h00b1 = h00b0 + bandStride;
  const float* h01b1 = h01b0 + bandStride;
  const float* h10b1 = h10b0 + bandStride;
  const float* h11b1 = h11b0 + bandStride;
  const float* h00b2 = h00b0 + 2*bandStride;
  const float* h01b2 = h01b0 + 2*bandStride;
  const float* h10b2 = h10b0 + 2*bandStride;
  const float* h11b2 = h11b0 + 2*bandStride;

  int j1 = jj - 6;   if (j1 < 0)     j1 += ROWF;   // slot tid
  int j2 = jj + 250; if (j2 >= ROWF) j2 -= ROWF;   // slot 256+tid (tid<12)
  const bool halo = (tid < 12);

  // circular window, period 5 (row i -> slot i%5), static after unroll
  float wla0e[5], wla0o[5], wla1e[5], wla1o[5];
  float wha0e[5], wha0o[5], wha1e[5], wha1o[5];
#pragma unroll
  for (int k = 0; k < 5; ++k) {
    wla0e[k]=0.f; wla0o[k]=0.f; wla1e[k]=0.f; wla1o[k]=0.f;
    wha0e[k]=0.f; wha0o[k]=0.f; wha1e[k]=0.f; wha1o[k]=0.f;
  }

  const int s0 = blockIdx.y * SEG;
  float* outb = out + b * OPLANE;

  float4 G0, G1, G2, G3;
  float4 Hh0 = make_float4(0.f,0.f,0.f,0.f), Hh1 = Hh0, Hh2 = Hh0, Hh3 = Hh0;

#define S2_LOAD(I)                                                           \
  {                                                                          \
    const int rb_ = ((s0 - 2 + (I)) & (HIN - 1)) * ROWF;                     \
    const int o1_ = rb_ + j1;                                                \
    G0 = make_float4(a0[o1_], a1[o1_], a2[o1_], a3[o1_]);                    \
    G1 = make_float4(h00b0[o1_], h11b0[o1_], h01b0[o1_], h10b0[o1_]);        \
    G2 = make_float4(h00b1[o1_], h11b1[o1_], h01b1[o1_], h10b1[o1_]);        \
    G3 = make_float4(h00b2[o1_], h11b2[o1_], h01b2[o1_], h10b2[o1_]);        \
    if (halo) {                                                              \
      const int o2_ = rb_ + j2;                                              \
      Hh0 = make_float4(a0[o2_], a1[o2_], a2[o2_], a3[o2_]);                 \
      Hh1 = make_float4(h00b0[o2_], h11b0[o2_], h01b0[o2_], h10b0[o2_]);     \
      Hh2 = make_float4(h00b1[o2_], h11b1[o2_], h01b1[o2_], h10b1[o2_]);     \
      Hh3 = make_float4(h00b2[o2_], h11b2[o2_], h01b2[o2_], h10b2[o2_]);     \
    }                                                                        \
  }

// pre-butterfly + 0.5-fold, then 4x ds_write_b128.
#define S2_WRITE()                                                           \
  {                                                                          \
    float4* w_ = lds4 + tid * PITCH;                                         \
    w_[0] = make_float4(G0.x*0.5f, G0.y*0.5f, G0.z*0.5f, G0.w*0.5f);         \
    w_[1] = make_float4((G1.x+G1.y)*KH, (G1.x-G1.y)*KH,                      \
                        (G1.z+G1.w)*KH, (G1.z-G1.w)*KH);                     \
    w_[2] = make_float4((G2.x+G2.y)*KH, (G2.x-G2.y)*KH,                      \
                        (G2.z+G2.w)*KH, (G2.z-G2.w)*KH);                     \
    w_[3] = make_float4((G3.x+G3.y)*KH, (G3.x-G3.y)*KH,                      \
                        (G3.z+G3.w)*KH, (G3.z-G3.w)*KH);                     \
    if (halo) {                                                              \
      float4* w2_ = lds4 + (256 + tid) * PITCH;                              \
      w2_[0] = make_float4(Hh0.x*0.5f, Hh0.y*0.5f, Hh0.z*0.5f, Hh0.w*0.5f);  \
      w2_[1] = make_float4((Hh1.x+Hh1.y)*KH, (Hh1.x-Hh1.y)*KH,               \
                           (Hh1.z+Hh1.w)*KH, (Hh1.z-Hh1.w)*KH);              \
      w2_[2] = make_float4((Hh2.x+Hh2.y)*KH, (Hh2.x-Hh2.y)*KH,               \
                           (Hh2.z+Hh2.w)*KH, (Hh2.z-Hh2.w)*KH);              \
      w2_[3] = make_float4((Hh3.x+Hh3.y)*KH, (Hh3.x-Hh3.y)*KH,               \
                           (Hh3.z+Hh3.w)*KH, (Hh3.z-Hh3.w)*KH);              \
    }                                                                        \
  }

  // ---- prologue: stage row 0 ----
  S2_LOAD(0);
  S2_WRITE();
  __syncthreads();

#pragma unroll 1
  for (int uo = 0; uo < 3; ++uo) {
#pragma unroll
    for (int k = 0; k < 5; ++k) {
      const int i = uo * 5 + k;           // window slot = k (static; i%5==k)
      if (i < NI) {
        if (i < NI - 1) {
          S2_LOAD(i + 1);
          __builtin_amdgcn_sched_barrier(0);  // keep load issue at phase top
        }

        // ---- column pass from lds4: taps at slot tid + 12 - 3p ----
        float A0e=0.f,A0o=0.f,A1e=0.f,A1o=0.f, H0e=0.f,H0o=0.f,H1e=0.f,H1o=0.f;
#pragma unroll
        for (int p = 0; p < 5; ++p) {
          const float4* qp = lds4 + (tid + (12 - 3*p)) * PITCH;
          const float4 q0 = qp[0], q1 = qp[1], q2 = qp[2], q3 = qp[3];
          const float a0e = c_first[0][9-2*p][0], a0o = c_first[0][8-2*p][0];
          const float b0e = c_first[0][9-2*p][1], b0o = c_first[0][8-2*p][1];
          const float a1e = c_first[1][9-2*p][0], a1o = c_first[1][8-2*p][0];
          const float b1e = c_first[1][9-2*p][1], b1o = c_first[1][8-2*p][1];
          // lo2 terms (q0 = 0.5*(v00,v01,v10,v11))
          A0e += a0e*q0.x + a1e*q0.y;   A0o += a0o*q0.x + a1o*q0.y;
          A1e += a0e*q0.z + a1e*q0.w;   A1o += a0o*q0.z + a1o*q0.w;
          // LH band: q1 = (s1,d1,s2,d2)
          A0e += b0e*q1.x + b1e*q1.z;   A0o += b0o*q1.x + b1o*q1.z;
          A1e += b0e*q1.w + b1e*q1.y;   A1o += b0o*q1.w + b1o*q1.y;
          // HL band
          H0e += a0e*q2.x + a1e*q2.z;   H0o += a0o*q2.x + a1o*q2.z;
          H1e += a0e*q2.w + a1e*q2.y;   H1o += a0o*q2.w + a1o*q2.y;
          // HH band
          H0e += b0e*q3.x + b1e*q3.z;   H0o += b0o*q3.x + b1o*q3.z;
          H1e += b0e*q3.w + b1e*q3.y;   H1o += b0o*q3.w + b1o*q3.y;
        }
        wla0e[k]=A0e; wla0o[k]=A0o; wla1e[k]=A1e; wla1o[k]=A1o;
        wha0e[k]=H0e; wha0o[k]=H0o; wha1e[k]=H1e; wha1o[k]=H1o;

        if (i >= 4) {
          const int s = s0 + i - 4;
          float o00=0.f, o01=0.f, o10=0.f, o11=0.f;
#pragma unroll
          for (int p = 0; p < 5; ++p) {
            const int kk = (k - p + 5) % 5;   // static
            const float f00 = c_first[0][9-2*p][0], g00 = c_first[0][9-2*p][1];
            const float f01 = c_first[0][8-2*p][0], g01 = c_first[0][8-2*p][1];
            const float f10 = c_first[1][9-2*p][0], g10 = c_first[1][9-2*p][1];
            const float f11 = c_first[1][8-2*p][0], g11 = c_first[1][8-2*p][1];
            o00 += f00*wla0e[kk] + g00*wha0e[kk] + f10*wla1e[kk] + g10*wha1e[kk];
            o01 += f00*wla0o[kk] + g00*wha0o[kk] + f10*wla1o[kk] + g10*wha1o[kk];
            o10 += f01*wla0e[kk] + g01*wha0e[kk] + f11*wla1e[kk] + g11*wha1e[kk];
            o11 += f01*wla0o[kk] + g01*wha0o[kk] + f11*wla1o[kk] + g11*wha1o[kk];
          }
          float* q = outb + (2*s) * ROWO + (2*t) * C + c;
          q[0]        = o00;   // 0.5 folded into staging
          q[C]        = o01;
          q[ROWO]     = o10;
          q[ROWO + C] = o11;
        }

        __syncthreads();                  // B1: all reads of lds4 complete
        if (i < NI - 1) {
          S2_WRITE();                     // overwrite with row i+1
        }
        __syncthreads();                  // B2: writes visible
      }
    }
  }
#undef S2_LOAD
#undef S2_WRITE
}

extern "C" void kernel_launch(void* const* d_in, const int* in_sizes, int n_in,
                              void* d_out, int out_size, void* d_ws, size_t ws_size,
                              hipStream_t stream) {
  const float* highs0 = (const float*)d_in[0];  // (2,2,3,16,256,256,3)
  const float* highs1 = (const float*)d_in[1];  // (2,2,3,16,128,128,3)
  const float* lows   = (const float*)d_in[2];  // (2,2,16,128,128,3)
  float* out = (float*)d_out;                   // (16,512,512,3)
  float* lo2 = (float*)d_ws;                    // 50.3 MB

  // Stage 1 (R19 form): 3 x-blocks of 128; 8 segments of 16; 4x16 planes
  dim3 b1(128), g1(3, 8, 64);
  hipLaunchKernelGGL(idtcwt_stage1, g1, b1, 0, stream, lows, highs1, lo2);

  // Stage 2: 32 row segments of 8; 16 batches -> 1536 blocks = 6/CU
  dim3 b2(256), g2(3, 32, 16);
  hipLaunchKernelGGL(idtcwt_stage2, g2, b2, 0, stream, lo2, highs0, out);
}

// Round 21
// 105.579 us; speedup vs baseline: 3.0147x; 3.0147x over previous
//
#include <hip/hip_runtime.h>

#define INV_SQRT2 0.70710678118654752440f
#define KH 0.35355339059327376220f   // INV_SQRT2 * 0.5 (output scale folded in)

// Stage-2 filter table as constexpr: compile-time indices after unroll ->
// coefficients fold to immediates; structural zeros kill 20% of FMAs.
constexpr float c_first[2][10][2] = {
  { { 0.00000000000000f,  0.00000000000000f},
    {-0.08838834764832f, -0.01122679215254f},
    { 0.08838834764832f,  0.01122679215254f},
    { 0.69587998903400f,  0.08838834764832f},
    { 0.69587998903400f,  0.08838834764832f},
    { 0.08838834764832f, -0.69587998903400f},
    {-0.08838834764832f,  0.69587998903400f},
    { 0.01122679215254f, -0.08838834764832f},
    { 0.01122679215254f, -0.08838834764832f},
    { 0.00000000000000f,  0.00000000000000f} },
  { { 0.01122679215254f,  0.00000000000000f},
    { 0.01122679215254f,  0.00000000000000f},
    {-0.08838834764832f, -0.08838834764832f},
    { 0.08838834764832f, -0.08838834764832f},
    { 0.69587998903400f,  0.69587998903400f},
    { 0.69587998903400f, -0.69587998903400f},
    { 0.08838834764832f,  0.08838834764832f},
    {-0.08838834764832f,  0.08838834764832f},
    { 0.00000000000000f,  0.01122679215254f},
    { 0.00000000000000f, -0.01122679215254f} }
};

// Q-shift table, constexpr: stage1 dispatches a templated body per (M,N)
// combo, so all indices are compile-time -> immediates + zero folding.
constexpr float cq[2][10][2] = {
  { { 0.03516384f,  0.00000000f},
    { 0.00000000f,  0.00000000f},
    {-0.08832942f, -0.11430184f},
    { 0.23389032f,  0.00000000f},
    { 0.76027237f,  0.58751830f},
    { 0.58751830f, -0.76027237f},
    { 0.00000000f,  0.23389032f},
    {-0.11430184f,  0.08832942f},
    { 0.00000000f,  0.00000000f},
    { 0.00000000f, -0.03516384f} },
  { { 0.00000000f, -0.03516384f},
    { 0.00000000f,  0.00000000f},
    {-0.11430184f,  0.08832942f},
    { 0.00000000f,  0.23389032f},
    { 0.58751830f, -0.76027237f},
    { 0.76027237f,  0.58751830f},
    { 0.23389032f,  0.00000000f},
    {-0.08832942f, -0.11430184f},
    { 0.00000000f,  0.00000000f},
    { 0.03516384f,  0.00000000f} }
};

// ---------------------------------------------------------------------------
// Stage 1: LDS-row-staged (R19 proven, ~20.5us). Reg-staged loads ->
// pre-butterfly -> ds_write; single buffer + split barriers; planar
// [array][slot] pitch 144. Butterfly sign compile-time; K folds into
// coefficient immediates. LDS padded to 27,200 B -> 6 blocks/CU.
// ---------------------------------------------------------------------------
template<int M, int N>
__device__ __forceinline__ void s1_body(
    const float* __restrict__ lows, const float* __restrict__ highs1,
    float* __restrict__ lo2, float* __restrict__ lds)
{
  constexpr int HIN = 128, WIN = 128, C = 3, B = 16;
  constexpr int ROWF  = WIN * C;        // 384
  constexpr int ROWO  = 2 * WIN * C;    // 768
  constexpr int PLANE = HIN * WIN * C;  // 49152
  constexpr int SEG   = 16;
  constexpr int NI    = SEG + 4;        // 20 row phases
  constexpr int PITCH = 144;            // dwords per array slice (140 used)
  constexpr int combo = M * 2 + N;
  constexpr int pa = (M == N) ? 0 : 1;
  constexpr int pb = (M == N) ? 3 : 2;
  constexpr float K = INV_SQRT2;

  const int tid = threadIdx.x;          // 0..127
  const int jj  = blockIdx.x * 128 + tid;  // 0..383 = (t,c)
  const int c   = jj % 3;
  const int t   = jj / 3;
  const int b   = blockIdx.z & 15;

  const float* lo = lows + (combo * B + b) * PLANE;
  const int bandStride = B * PLANE;
  const float* hA = highs1 + (pa * 3 * B + b) * PLANE;
  const float* hB = highs1 + (pb * 3 * B + b) * PLANE;

  int j1 = jj - 6;   if (j1 < 0)     j1 += ROWF;   // slot tid (full wave)
  int j2 = jj + 122; if (j2 >= ROWF) j2 -= ROWF;   // slot 128+tid (tid<12)
  const bool halo = (tid < 12);

  float lae[5], lao[5], hae[5], hao[5];
#pragma unroll
  for (int k = 0; k < 5; ++k) { lae[k]=0.f; lao[k]=0.f; hae[k]=0.f; hao[k]=0.f; }

  const int s0 = blockIdx.y * SEG;
  float* outp = lo2 + (combo * B + b) * (4 * PLANE);

  float rl, rA0, rB0, rA1, rB1, rA2, rB2;
  float hl = 0.f, hA0v = 0.f, hB0v = 0.f, hA1v = 0.f,
        hB1v = 0.f, hA2v = 0.f, hB2v = 0.f;

#define BFY(a_, b_) ((M == 0) ? ((a_) + (b_)) : ((a_) - (b_)))

#define S1_LOAD(I)                                                           \
  {                                                                          \
    const int rb_ = ((s0 - 2 + (I)) & (HIN - 1)) * ROWF;                     \
    rl  = lo[rb_ + j1];                                                      \
    rA0 = hA[rb_ + j1];                rB0 = hB[rb_ + j1];                   \
    rA1 = hA[rb_ + j1 + bandStride];   rB1 = hB[rb_ + j1 + bandStride];      \
    rA2 = hA[rb_ + j1 + 2*bandStride]; rB2 = hB[rb_ + j1 + 2*bandStride];    \
    if (halo) {                                                              \
      hl   = lo[rb_ + j2];                                                   \
      hA0v = hA[rb_ + j2];                hB0v = hB[rb_ + j2];               \
      hA1v = hA[rb_ + j2 + bandStride];   hB1v = hB[rb_ + j2 + bandStride];  \
      hA2v = hA[rb_ + j2 + 2*bandStride]; hB2v = hB[rb_ + j2 + 2*bandStride];\
    }                                                                        \
  }

#define S1_WRITE()                                                           \
  {                                                                          \
    lds[0*PITCH + tid] = rl;                                                 \
    lds[1*PITCH + tid] = BFY(rA0, rB0);                                      \
    lds[2*PITCH + tid] = BFY(rA1, rB1);                                      \
    lds[3*PITCH + tid] = BFY(rA2, rB2);                                      \
    if (halo) {                                                              \
      lds[0*PITCH + 128 + tid] = hl;                                         \
      lds[1*PITCH + 128 + tid] = BFY(hA0v, hB0v);                            \
      lds[2*PITCH + 128 + tid] = BFY(hA1v, hB1v);                            \
      lds[3*PITCH + 128 + tid] = BFY(hA2v, hB2v);                            \
    }                                                                        \
  }

  S1_LOAD(0);
  S1_WRITE();
  __syncthreads();

#pragma unroll 1
  for (int uo = 0; uo < 4; ++uo) {
#pragma unroll
    for (int k = 0; k < 5; ++k) {
      const int i = uo * 5 + k;           // window slot = k (static; i%5==k)

      if (i < NI - 1) {
        S1_LOAD(i + 1);
        __builtin_amdgcn_sched_barrier(0);
      }

      float aLe=0.f, aLo=0.f, aHe=0.f, aHo=0.f;
#pragma unroll
      for (int p = 0; p < 5; ++p) {
        const int sl = tid + (12 - 3*p);
        const float lv  = lds[0*PITCH + sl];
        const float lhv = lds[1*PITCH + sl];
        const float hlv = lds[2*PITCH + sl];
        const float hhv = lds[3*PITCH + sl];
        const float ce0  = cq[N][9-2*p][0];
        const float co0  = cq[N][8-2*p][0];
        const float ce1K = cq[N][9-2*p][1] * K;
        const float co1K = cq[N][8-2*p][1] * K;
        const float ce0K = ce0 * K;
        const float co0K = co0 * K;
        aLe += ce0  * lv  + ce1K * lhv;
        aLo += co0  * lv  + co1K * lhv;
        aHe += ce0K * hlv + ce1K * hhv;
        aHo += co0K * hlv + co1K * hhv;
      }
      lae[k]=aLe; lao[k]=aLo; hae[k]=aHe; hao[k]=aHo;

      if (i >= 4) {
        const int s = s0 + i - 4;
        float o00=0.f, o01=0.f, o10=0.f, o11=0.f;
#pragma unroll
        for (int p = 0; p < 5; ++p) {
          const int kk = (k - p + 5) % 5;
          const float f0l = cq[M][9-2*p][0], f0h = cq[M][9-2*p][1];
          const float f1l = cq[M][8-2*p][0], f1h = cq[M][8-2*p][1];
          o00 += f0l*lae[kk] + f0h*hae[kk];
          o01 += f0l*lao[kk] + f0h*hao[kk];
          o10 += f1l*lae[kk] + f1h*hae[kk];
          o11 += f1l*lao[kk] + f1h*hao[kk];
        }
        float* q = outp + (2*s) * ROWO + (2*t) * C + c;
        q[0]        = o00;
        q[C]        = o01;
        q[ROWO]     = o10;
        q[ROWO + C] = o11;
      }

      __syncthreads();
      if (i < NI - 1) {
        S1_WRITE();
      }
      __syncthreads();
    }
  }
#undef S1_LOAD
#undef S1_WRITE
#undef BFY
}

__global__ __launch_bounds__(128, 3) void idtcwt_stage1(
    const float* __restrict__ lows, const float* __restrict__ highs1,
    float* __restrict__ lo2)
{
  __shared__ float s1lds[6800];         // 27,200 B -> 6 blocks/CU
  const int combo = blockIdx.z >> 4;
  if      (combo == 0) s1_body<0,0>(lows, highs1, lo2, s1lds);
  else if (combo == 1) s1_body<0,1>(lows, highs1, lo2, s1lds);
  else if (combo == 2) s1_body<1,0>(lows, highs1, lo2, s1lds);
  else                 s1_body<1,1>(lows, highs1, lo2, s1lds);
}

// ---------------------------------------------------------------------------
// Stage 2: R15/R19 proven form (~84us): one row/phase, one prefetch set,
// single-buffer LDS + split barriers, padded to 49,152 B (3 blocks/CU ->
// VGPR budget ~170, no spill at VGPR=68), SEG=16, 12 waves/CU.
// FINAL: occupancy axis exhausted — HW VGPR quantization (8/4/2 waves at
// 64/128/256 regs) makes every higher-occupancy target spill (R10/11/20);
// SEG=8 work overhead cancels wave gains (R13); async DMA fails correctness
// (R16/17). This is the measured floor of the design space.
// ---------------------------------------------------------------------------
__global__ __launch_bounds__(256, 4) void idtcwt_stage2(
    const float* __restrict__ lo2, const float* __restrict__ highs0,
    float* __restrict__ out)
{
  constexpr int HIN = 256, WIN = 256, C = 3, B = 16;
  constexpr int ROWF  = WIN * C;        // 768 floats per input row
  constexpr int ROWO  = 2 * WIN * C;    // 1536
  constexpr int PLANE = HIN * WIN * C;  // 196608
  constexpr int OPLANE = 512 * 512 * C; // 786432
  constexpr int SEG   = 16;
  constexpr int NI    = SEG + 4;        // 20 row phases
  constexpr int PITCH = 5;              // float4s per slot (16 arrays + pad)
  constexpr int LDSV4 = 3072;           // 49,152 B -> 3 blk/CU, budget ~170

  __shared__ float4 lds4[LDSV4];        // 21,760 B used; padded for budget

  const int tid = threadIdx.x;
  const int jj  = blockIdx.x * 256 + tid;  // 0..767 = (t,c)
  const int c   = jj % 3;
  const int t   = jj / 3;
  const int b   = blockIdx.z;

  const int bandStride = B * PLANE;
  const float* a0  = lo2 + (0 * B + b) * PLANE;           // l00
  const float* a1  = lo2 + (1 * B + b) * PLANE;           // l01
  const float* a2  = lo2 + (2 * B + b) * PLANE;           // l10
  const float* a3  = lo2 + (3 * B + b) * PLANE;           // l11
  const float* h00b0 = highs0 + (0 * 3 * B + b) * PLANE;
  const float* h01b0 = highs0 + (1 * 3 * B + b) * PLANE;
  const float* h10b0 = highs0 + (2 * 3 * B + b) * PLANE;
  const float* h11b0 = highs0 + (3 * 3 * B + b) * PLANE;
  const float* h00b1 = h00b0 + bandStride;
  const float* h01b1 = h01b0 + bandStride;
  const float* h10b1 = h10b0 + bandStride;
  const float* h11b1 = h11b0 + bandStride;
  const float* h00b2 = h00b0 + 2*bandStride;
  const float* h01b2 = h01b0 + 2*bandStride;
  const float* h10b2 = h10b0 + 2*bandStride;
  const float* h11b2 = h11b0 + 2*bandStride;

  int j1 = jj - 6;   if (j1 < 0)     j1 += ROWF;   // slot tid
  int j2 = jj + 250; if (j2 >= ROWF) j2 -= ROWF;   // slot 256+tid (tid<12)
  const bool halo = (tid < 12);

  // circular window, period 5 (row i -> slot i%5), static after unroll
  float wla0e[5], wla0o[5], wla1e[5], wla1o[5];
  float wha0e[5], wha0o[5], wha1e[5], wha1o[5];
#pragma unroll
  for (int k = 0; k < 5; ++k) {
    wla0e[k]=0.f; wla0o[k]=0.f; wla1e[k]=0.f; wla1o[k]=0.f;
    wha0e[k]=0.f; wha0o[k]=0.f; wha1e[k]=0.f; wha1o[k]=0.f;
  }

  const int s0 = blockIdx.y * SEG;
  float* outb = out + b * OPLANE;

  float4 G0, G1, G2, G3;
  float4 Hh0 = make_float4(0.f,0.f,0.f,0.f), Hh1 = Hh0, Hh2 = Hh0, Hh3 = Hh0;

#define S2_LOAD(I)                                                           \
  {                                                                          \
    const int rb_ = ((s0 - 2 + (I)) & (HIN - 1)) * ROWF;                     \
    const int o1_ = rb_ + j1;                                                \
    G0 = make_float4(a0[o1_], a1[o1_], a2[o1_], a3[o1_]);                    \
    G1 = make_float4(h00b0[o1_], h11b0[o1_], h01b0[o1_], h10b0[o1_]);        \
    G2 = make_float4(h00b1[o1_], h11b1[o1_], h01b1[o1_], h10b1[o1_]);        \
    G3 = make_float4(h00b2[o1_], h11b2[o1_], h01b2[o1_], h10b2[o1_]);        \
    if (halo) {                                                              \
      const int o2_ = rb_ + j2;                                              \
      Hh0 = make_float4(a0[o2_], a1[o2_], a2[o2_], a3[o2_]);                 \
      Hh1 = make_float4(h00b0[o2_], h11b0[o2_], h01b0[o2_], h10b0[o2_]);     \
      Hh2 = make_float4(h00b1[o2_], h11b1[o2_], h01b1[o2_], h10b1[o2_]);     \
      Hh3 = make_float4(h00b2[o2_], h11b2[o2_], h01b2[o2_], h10b2[o2_]);     \
    }                                                                        \
  }

// pre-butterfly + 0.5-fold, then 4x ds_write_b128.
#define S2_WRITE()                                                           \
  {                                                                          \
    float4* w_ = lds4 + tid * PITCH;                                         \
    w_[0] = make_float4(G0.x*0.5f, G0.y*0.5f, G0.z*0.5f, G0.w*0.5f);         \
    w_[1] = make_float4((G1.x+G1.y)*KH, (G1.x-G1.y)*KH,                      \
                        (G1.z+G1.w)*KH, (G1.z-G1.w)*KH);                     \
    w_[2] = make_float4((G2.x+G2.y)*KH, (G2.x-G2.y)*KH,                      \
                        (G2.z+G2.w)*KH, (G2.z-G2.w)*KH);                     \
    w_[3] = make_float4((G3.x+G3.y)*KH, (G3.x-G3.y)*KH,                      \
                        (G3.z+G3.w)*KH, (G3.z-G3.w)*KH);                     \
    if (halo) {                                                              \
      float4* w2_ = lds4 + (256 + tid) * PITCH;                              \
      w2_[0] = make_float4(Hh0.x*0.5f, Hh0.y*0.5f, Hh0.z*0.5f, Hh0.w*0.5f);  \
      w2_[1] = make_float4((Hh1.x+Hh1.y)*KH, (Hh1.x-Hh1.y)*KH,               \
                           (Hh1.z+Hh1.w)*KH, (Hh1.z-Hh1.w)*KH);              \
      w2_[2] = make_float4((Hh2.x+Hh2.y)*KH, (Hh2.x-Hh2.y)*KH,               \
                           (Hh2.z+Hh2.w)*KH, (Hh2.z-Hh2.w)*KH);              \
      w2_[3] = make_float4((Hh3.x+Hh3.y)*KH, (Hh3.x-Hh3.y)*KH,               \
                           (Hh3.z+Hh3.w)*KH, (Hh3.z-Hh3.w)*KH);              \
    }                                                                        \
  }

  // ---- prologue: stage row 0 ----
  S2_LOAD(0);
  S2_WRITE();
  __syncthreads();

#pragma unroll 1
  for (int uo = 0; uo < 4; ++uo) {
#pragma unroll
    for (int k = 0; k < 5; ++k) {
      const int i = uo * 5 + k;           // window slot = k (static; i%5==k)

      if (i < NI - 1) {
        S2_LOAD(i + 1);
        __builtin_amdgcn_sched_barrier(0);  // keep load issue at phase top
      }

      // ---- column pass from lds4: taps at slot tid + 12 - 3p ----
      float A0e=0.f,A0o=0.f,A1e=0.f,A1o=0.f, H0e=0.f,H0o=0.f,H1e=0.f,H1o=0.f;
#pragma unroll
      for (int p = 0; p < 5; ++p) {
        const float4* qp = lds4 + (tid + (12 - 3*p)) * PITCH;
        const float4 q0 = qp[0], q1 = qp[1], q2 = qp[2], q3 = qp[3];
        const float a0e = c_first[0][9-2*p][0], a0o = c_first[0][8-2*p][0];
        const float b0e = c_first[0][9-2*p][1], b0o = c_first[0][8-2*p][1];
        const float a1e = c_first[1][9-2*p][0], a1o = c_first[1][8-2*p][0];
        const float b1e = c_first[1][9-2*p][1], b1o = c_first[1][8-2*p][1];
        // lo2 terms (q0 = 0.5*(v00,v01,v10,v11))
        A0e += a0e*q0.x + a1e*q0.y;   A0o += a0o*q0.x + a1o*q0.y;
        A1e += a0e*q0.z + a1e*q0.w;   A1o += a0o*q0.z + a1o*q0.w;
        // LH band: q1 = (s1,d1,s2,d2)
        A0e += b0e*q1.x + b1e*q1.z;   A0o += b0o*q1.x + b1o*q1.z;
        A1e += b0e*q1.w + b1e*q1.y;   A1o += b0o*q1.w + b1o*q1.y;
        // HL band
        H0e += a0e*q2.x + a1e*q2.z;   H0o += a0o*q2.x + a1o*q2.z;
        H1e += a0e*q2.w + a1e*q2.y;   H1o += a0o*q2.w + a1o*q2.y;
        // HH band
        H0e += b0e*q3.x + b1e*q3.z;   H0o += b0o*q3.x + b1o*q3.z;
        H1e += b0e*q3.w + b1e*q3.y;   H1o += b0o*q3.w + b1o*q3.y;
      }
      wla0e[k]=A0e; wla0o[k]=A0o; wla1e[k]=A1e; wla1o[k]=A1o;
      wha0e[k]=H0e; wha0o[k]=H0o; wha1e[k]=H1e; wha1o[k]=H1o;

      if (i >= 4) {
        const int s = s0 + i - 4;
        float o00=0.f, o01=0.f, o10=0.f, o11=0.f;
#pragma unroll
        for (int p = 0; p < 5; ++p) {
          const int kk = (k - p + 5) % 5;   // static
          const float f00 = c_first[0][9-2*p][0], g00 = c_first[0][9-2*p][1];
          const float f01 = c_first[0][8-2*p][0], g01 = c_first[0][8-2*p][1];
          const float f10 = c_first[1][9-2*p][0], g10 = c_first[1][9-2*p][1];
          const float f11 = c_first[1][8-2*p][0], g11 = c_first[1][8-2*p][1];
          o00 += f00*wla0e[kk] + g00*wha0e[kk] + f10*wla1e[kk] + g10*wha1e[kk];
          o01 += f00*wla0o[kk] + g00*wha0o[kk] + f10*wla1o[kk] + g10*wha1o[kk];
          o10 += f01*wla0e[kk] + g01*wha0e[kk] + f11*wla1e[kk] + g11*wha1e[kk];
          o11 += f01*wla0o[kk] + g01*wha0o[kk] + f11*wla1o[kk] + g11*wha1o[kk];
        }
        float* q = outb + (2*s) * ROWO + (2*t) * C + c;
        q[0]        = o00;   // 0.5 folded into staging
        q[C]        = o01;
        q[ROWO]     = o10;
        q[ROWO + C] = o11;
      }

      __syncthreads();                    // B1: all reads of lds4 complete
      if (i < NI - 1) {
        S2_WRITE();                       // overwrite with row i+1
      }
      __syncthreads();                    // B2: writes visible
    }
  }
#undef S2_LOAD
#undef S2_WRITE
}

extern "C" void kernel_launch(void* const* d_in, const int* in_sizes, int n_in,
                              void* d_out, int out_size, void* d_ws, size_t ws_size,
                              hipStream_t stream) {
  const float* highs0 = (const float*)d_in[0];  // (2,2,3,16,256,256,3)
  const float* highs1 = (const float*)d_in[1];  // (2,2,3,16,128,128,3)
  const float* lows   = (const float*)d_in[2];  // (2,2,16,128,128,3)
  float* out = (float*)d_out;                   // (16,512,512,3)
  float* lo2 = (float*)d_ws;                    // 50.3 MB

  // Stage 1 (R19 form): 3 x-blocks of 128; 8 segments of 16; 4x16 planes
  dim3 b1(128), g1(3, 8, 64);
  hipLaunchKernelGGL(idtcwt_stage1, g1, b1, 0, stream, lows, highs1, lo2);

  // Stage 2 (R19 form): 16 row segments of 16; 16 batches -> 768 blocks
  dim3 b2(256), g2(3, 16, 16);
  hipLaunchKernelGGL(idtcwt_stage2, g2, b2, 0, stream, lo2, highs0, out);
}